// Round 1
// baseline (202.560 us; speedup 1.0000x reference)
//
#include <hip/hip_runtime.h>
#include <hip/hip_bf16.h>

// Problem: out[32768,128] = sigmoid(x[32768,1024] @ W[1024,128] + b[128]), all fp32.
// R5: counted-vmcnt pipeline (T3+T4). 8 K-phases of 128, LDS double-buffered
//     (2 x 32KB). W staged with global_load_lds width=16 (no VGPR round trip).
//     Raw s_barrier + s_waitcnt vmcnt(16): stage(p+1)+A(p+1) retire at end of
//     phase p while stage(p+2)+A(p+2) stay in flight -> VM queue never drains
//     in the main loop (the old kernel drained it 8x via __syncthreads).

typedef __bf16 bf16x8 __attribute__((ext_vector_type(8)));
typedef float  f32x4  __attribute__((ext_vector_type(4)));

#define DIM   1024
#define NT    128
#define BATCH 32768

#define WAITVM16()  asm volatile("s_waitcnt vmcnt(16)" ::: "memory")
#define WAITVM0()   asm volatile("s_waitcnt vmcnt(0)"  ::: "memory")
#define WAITLGKM0() asm volatile("s_waitcnt lgkmcnt(0)" ::: "memory")
#define CFENCE()    asm volatile("" ::: "memory")
#define BAR()       __builtin_amdgcn_s_barrier()

// ---------------------------------------------------------------------------
// Prep: W[k][n] fp32 -> bf16 in B-fragment order (unchanged from R4).
// wsW[ ((s*8 + c)*64 + lane)*8 + j ] = W[ s*32 + (lane>>4)*8 + j ][ c*16 + (lane&15) ]
// Phase p (k-chunk of 128 = 4 k-steps) occupies the contiguous frag-unit range
// [p*2048, (p+1)*2048) -> 32 KB, stageable linearly.
// ---------------------------------------------------------------------------
__global__ __launch_bounds__(256) void prep_w(const float* __restrict__ W,
                                              __bf16* __restrict__ wsW) {
    int idx = blockIdx.x * 256 + threadIdx.x;   // 0 .. 131071
    int j = idx & 7;
    int l = (idx >> 3) & 63;
    int c = (idx >> 9) & 7;
    int s = idx >> 12;
    int k = s * 32 + (l >> 4) * 8 + j;
    int n = c * 16 + (l & 15);
    wsW[idx] = (__bf16)W[k * NT + n];
}

__device__ __forceinline__ bf16x8 cvt_bf16x8(float4 a0, float4 a1) {
    bf16x8 af;
    af[0] = (__bf16)a0.x; af[1] = (__bf16)a0.y;
    af[2] = (__bf16)a0.z; af[3] = (__bf16)a0.w;
    af[4] = (__bf16)a1.x; af[5] = (__bf16)a1.y;
    af[6] = (__bf16)a1.z; af[7] = (__bf16)a1.w;
    return af;
}

// Stage 8 KB per wave: 8 x global_load_lds dwordx4, wave-uniform LDS base,
// per-lane global src (linear, matches hardware base + lane*16 layout).
__device__ __forceinline__ void stage8(const bf16x8* g, bf16x8* l) {
#pragma unroll
    for (int i = 0; i < 8; ++i)
        __builtin_amdgcn_global_load_lds(
            (const __attribute__((address_space(1))) void*)(g + i * 64),
            (__attribute__((address_space(3))) void*)(l + i * 64),
            16, 0, 0);
}

// A-burst for one phase: 8 x float4 (4 k-steps x 32B/lane), constant-indexed.
__device__ __forceinline__ void loada8(float4* S, const float* xA, int P) {
#pragma unroll
    for (int sl = 0; sl < 4; ++sl) {
        const float* ap = xA + (size_t)(P * 4 + sl) * 32;
        S[2 * sl]     = *(const float4*)ap;
        S[2 * sl + 1] = *(const float4*)(ap + 4);
    }
}

// One phase of compute: 4 k-steps x 8 col-frags = 32 MFMA from LDS buffer bb.
__device__ __forceinline__ void compute8(const float4* S, const bf16x8* bb,
                                         int lane, f32x4* acc) {
#pragma unroll
    for (int sl = 0; sl < 4; ++sl) {
        const bf16x8 af = cvt_bf16x8(S[2 * sl], S[2 * sl + 1]);
#pragma unroll
        for (int c = 0; c < 8; ++c) {
            const bf16x8 bf = bb[(sl * 8 + c) * 64 + lane];
            acc[c] = __builtin_amdgcn_mfma_f32_16x16x32_bf16(af, bf, acc[c], 0, 0, 0);
        }
    }
}

// ---------------------------------------------------------------------------
// Main: block = 256 threads = 4 waves; wave tile 16 rows x 128 cols.
// Grid = 512 (2 blocks/CU, 64 KB LDS each). 8 phases, 2-deep pipeline:
// entering phase p: W(p),A(p) resident; W(p+1),A(p+1) in flight (16 VMEM ops).
// A-frag (16x16x32): lane holds A[m = lane&15][k = (lane>>4)*8 + j]
// B-frag:            lane holds B[k = (lane>>4)*8 + j][n = lane&15]
// C/D:               col = lane&15, row = (lane>>4)*4 + reg
// ---------------------------------------------------------------------------
__global__ __launch_bounds__(256, 2) void gemm_bias_sigmoid(
        const float* __restrict__ x,
        const __hip_bfloat16* __restrict__ wsWh,
        const float* __restrict__ bias,
        float* __restrict__ out) {
    const bf16x8* __restrict__ wsW8 = (const bf16x8*)wsWh;  // frag units of 16B
    __shared__ bf16x8 ldsW[2][2048];                        // 2 x 32 KB

    const int tid  = threadIdx.x;
    const int lane = tid & 63;
    const int wave = tid >> 6;
    const int q    = lane >> 4;
    const int r    = lane & 15;
    const int row0 = blockIdx.x * 64 + wave * 16;

    const float* xA = x + (size_t)(row0 + r) * DIM + q * 8;
    // wave stages frag-units [wave*512 + i*64 + lane] of each 2048-unit phase
    const bf16x8* gW = wsW8 + wave * 512 + lane;
    bf16x8* lW0 = &ldsW[0][wave * 512];
    bf16x8* lW1 = &ldsW[1][wave * 512];

    f32x4 acc[8];
#pragma unroll
    for (int c = 0; c < 8; ++c)
        acc[c] = (f32x4){0.f, 0.f, 0.f, 0.f};

    float4 SA[8], SB[8];

    // ---- prologue: issue phases 0 and 1; wait only for phase 0 ----
    stage8(gW, lW0);                 // W(0) -> buf0   (8 VMEM)
    loada8(SA, xA, 0);               // A(0)           (8 VMEM)
    stage8(gW + 2048, lW1);          // W(1) -> buf1   (8 VMEM)
    loada8(SB, xA, 1);               // A(1)           (8 VMEM)
    WAITVM16();                      // W(0)+A(0) done; W(1)+A(1) in flight
    BAR(); CFENCE();

    // ---- steady phases 0..5: compute p, refill p+2 into the freed buffer ----
#define STEP(P, S, LWB, BB)                                        \
    compute8(S, BB, lane, acc);                                    \
    WAITLGKM0();                                                   \
    BAR(); CFENCE();          /* all waves done reading BB */      \
    stage8(gW + (size_t)(P + 2) * 2048, LWB); /* W(P+2) (8) */     \
    loada8(S, xA, P + 2);                     /* A(P+2) (8) */     \
    WAITVM16();               /* retire W(P+1)+A(P+1) */           \
    BAR(); CFENCE();          /* all waves' W(P+1) staged */

    STEP(0, SA, lW0, &ldsW[0][0])
    STEP(1, SB, lW1, &ldsW[1][0])
    STEP(2, SA, lW0, &ldsW[0][0])
    STEP(3, SB, lW1, &ldsW[1][0])
    STEP(4, SA, lW0, &ldsW[0][0])
    STEP(5, SB, lW1, &ldsW[1][0])
#undef STEP

    // ---- tail: phase 6 (drain W(7)+A(7)), phase 7 ----
    compute8(SA, &ldsW[0][0], lane, acc);
    WAITVM0();
    BAR(); CFENCE();
    compute8(SB, &ldsW[1][0], lane, acc);

    // ---- epilogue: bias + sigmoid + store ----
#pragma unroll
    for (int c = 0; c < 8; ++c) {
        const float bv = bias[c * 16 + r];
#pragma unroll
        for (int reg = 0; reg < 4; ++reg) {
            const int row = row0 + q * 4 + reg;
            float v = acc[c][reg] + bv;
            v = 1.0f / (1.0f + __expf(-v));
            out[(size_t)row * NT + c * 16 + r] = v;
        }
    }
}

extern "C" void kernel_launch(void* const* d_in, const int* in_sizes, int n_in,
                              void* d_out, int out_size, void* d_ws, size_t ws_size,
                              hipStream_t stream) {
    const float* x = (const float*)d_in[0];   // [32768,1024]
    const float* W = (const float*)d_in[1];   // [1024,128]
    const float* b = (const float*)d_in[2];   // [128]
    float* out     = (float*)d_out;           // [32768,128]
    __bf16* wsW    = (__bf16*)d_ws;           // 256 KB swizzled bf16 W

    prep_w<<<DIM * NT / 256, 256, 0, stream>>>(W, wsW);
    gemm_bias_sigmoid<<<BATCH / 64, 256, 0, stream>>>(
        x, (const __hip_bfloat16*)wsW, b, out);
}